// Round 7
// baseline (187.627 us; speedup 1.0000x reference)
//
#include <hip/hip_runtime.h>
#include <math.h>

#define IN_SIZE 128
#define E_SIZE  32
#define KDIM    160
#define BSHIFT  6                    // 64 nodes per bucket
#define BNODES  (1 << BSHIFT)
#define NBK_MAX 1024                 // nbk = ceil(50000/64) = 782 <= 1024
#define NSCAT   256                  // blocks for hist/scatter
#define LSORT   4096                 // LDS-sorted edge capacity per bucket (mean 2048, sigma 45)

// ---------------- per-block bucket histogram -> slab (no atomics to global) ----------------

__global__ __launch_bounds__(256) void k_bhist(
    const int* __restrict__ dst, int* __restrict__ slabA, int E, int nbk)
{
    __shared__ int hist[NBK_MAX];
    int tid = threadIdx.x;
    for (int k = tid; k < nbk; k += 256) hist[k] = 0;
    __syncthreads();
    int chunk = (E + NSCAT - 1) / NSCAT;
    int s = blockIdx.x * chunk;
    int e = s + chunk; if (e > E) e = E;
    for (int i = s + tid; i < e; i += 256)
        atomicAdd(&hist[dst[i] >> BSHIFT], 1);
    __syncthreads();
    for (int k = tid; k < nbk; k += 256)
        slabA[blockIdx.x * nbk + k] = hist[k];
}

// ---------------- single block: bucket bases + per-(block,bucket) write bases ----------------

__global__ __launch_bounds__(1024) void k_scan(
    const int* __restrict__ slabA, int* __restrict__ slabB,
    int* __restrict__ bktbase, int nbk, int E)
{
    __shared__ int s[1024];
    int tid = threadIdx.x;
    int total = 0;
    if (tid < nbk)
        for (int b = 0; b < NSCAT; ++b) total += slabA[b * nbk + tid];   // coalesced across tid
    s[tid] = total;
    __syncthreads();
    for (int off = 1; off < 1024; off <<= 1) {      // Hillis-Steele inclusive
        int add = (tid >= off) ? s[tid - off] : 0;
        __syncthreads();
        s[tid] += add;
        __syncthreads();
    }
    if (tid < nbk) {
        int run = s[tid] - total;                   // exclusive bucket base
        bktbase[tid] = run;
        for (int b = 0; b < NSCAT; ++b) {           // per-block write bases (tile bucket region)
            slabB[b * nbk + tid] = run;
            run += slabA[b * nbk + tid];
        }
    }
    if (tid == 0) bktbase[nbk] = E;
}

// ---------------- scatter with precomputed bases (single dst pass, LDS cursors only) ----------------
// bin entry packs (edge_id << 6) | (dst & 63); eid < 2^21 fits in 27 bits.

__global__ __launch_bounds__(256) void k_scatter(
    const int* __restrict__ dst, const int* __restrict__ slabB,
    int* __restrict__ bin, int E, int nbk)
{
    __shared__ int cur[NBK_MAX];
    int tid = threadIdx.x;
    for (int k = tid; k < nbk; k += 256) cur[k] = slabB[blockIdx.x * nbk + k];
    __syncthreads();
    int chunk = (E + NSCAT - 1) / NSCAT;
    int s = blockIdx.x * chunk;
    int e = s + chunk; if (e > E) e = E;
    for (int i = s + tid; i < e; i += 256) {
        int d = dst[i];
        int p = atomicAdd(&cur[d >> BSHIFT], 1);    // cursor holds GLOBAL position
        bin[p] = (i << BSHIFT) | (d & (BNODES - 1));
    }
}

// ---------------- fused per-bucket sort (LDS) + per-node aggregate ----------------
// 512 threads (8 waves) per bucket of 64 nodes; each wave aggregates 8 nodes.
// Within a wave: es = lane>>3 edge slot, q = lane&7 feature quarter (float4).

__device__ __forceinline__ float red_q(float x) {        // sum across q (lane bits 0..2)
    x += __shfl_xor(x, 1); x += __shfl_xor(x, 2); x += __shfl_xor(x, 4);
    return x;
}
__device__ __forceinline__ float red_es(float x) {       // sum across es (lane bits 3..5)
    x += __shfl_xor(x, 8); x += __shfl_xor(x, 16); x += __shfl_xor(x, 32);
    return x;
}
__device__ __forceinline__ float4 red_es4(float4 v) {
    v.x = red_es(v.x); v.y = red_es(v.y); v.z = red_es(v.z); v.w = red_es(v.w);
    return v;
}

__global__ __launch_bounds__(512, 4) void k_fill_node(
    const int* __restrict__ bktbase, const int* __restrict__ bin,
    const float* __restrict__ ef, int* __restrict__ eids_fb,
    float* __restrict__ agg, int N)
{
    __shared__ int cnt[BNODES];
    __shared__ int nb0[BNODES];
    __shared__ int lsort[LSORT];
    int b = blockIdx.x, tid = threadIdx.x;
    int s = bktbase[b], e = bktbase[b + 1];
    bool ovf = (e - s) > LSORT;                      // ~never for this input

    if (tid < BNODES) cnt[tid] = 0;
    __syncthreads();
    for (int k = s + tid; k < e; k += 512)
        atomicAdd(&cnt[bin[k] & (BNODES - 1)], 1);
    __syncthreads();
    if (tid < BNODES) {                              // wave 0: shuffle scan of 64 degrees
        int v = cnt[tid], x = v;
        #pragma unroll
        for (int off = 1; off < 64; off <<= 1) {
            int y = __shfl_up(x, off);
            if (tid >= off) x += y;
        }
        nb0[tid] = x - v;                            // local (0-based) node base
        cnt[tid] = 0;                                // reuse as cursor
    }
    __syncthreads();
    for (int k = s + tid; k < e; k += 512) {
        int pk = bin[k], ln = pk & (BNODES - 1);
        int p = nb0[ln] + atomicAdd(&cnt[ln], 1);
        if (ovf) eids_fb[s + p] = pk >> BSHIFT;
        else     lsort[p]       = pk >> BSHIFT;
    }
    __syncthreads();                                 // cnt[ln] now == degree

    int wv = tid >> 6, lane = tid & 63, es = lane >> 3, q = lane & 7;
    #pragma unroll 1
    for (int j = 0; j < 8; ++j) {
        int ln = wv * 8 + j;
        int nid = (b << BSHIFT) + ln;
        int start = nb0[ln], deg = cnt[ln];

        // preload up to 8 edge rows per slot into registers (eids from LDS)
        float4 fc[8];
        #pragma unroll
        for (int it = 0; it < 8; ++it) {
            int i = es + it * 8;
            float4 f = make_float4(0.f, 0.f, 0.f, 0.f);
            if (i < deg) {
                int eid = ovf ? eids_fb[s + start + i] : lsort[start + i];
                f = *(const float4*)&ef[(size_t)eid * E_SIZE + q * 4];
            }
            fc[it] = f;
        }

        // phase A: mean of in-edge features
        float4 esum = make_float4(0.f, 0.f, 0.f, 0.f);
        #pragma unroll
        for (int it = 0; it < 8; ++it) {
            esum.x += fc[it].x; esum.y += fc[it].y; esum.z += fc[it].z; esum.w += fc[it].w;
        }
        for (int i = es + 64; i < deg; i += 8) {     // deg>64 overflow: ~never
            int eid = ovf ? eids_fb[s + start + i] : lsort[start + i];
            float4 f = *(const float4*)&ef[(size_t)eid * E_SIZE + q * 4];
            esum.x += f.x; esum.y += f.y; esum.z += f.z; esum.w += f.w;
        }
        esum = red_es4(esum);
        float inv = (deg > 0) ? 1.f / (float)deg : 0.f;
        float4 hk = make_float4(esum.x * inv, esum.y * inv, esum.z * inv, esum.w * inv);
        float hn2 = hk.x * hk.x + hk.y * hk.y + hk.z * hk.z + hk.w * hk.w;
        hn2 = red_q(hn2);
        float t2h = 0.25f * hn2;                     // THRESH^2 * ||hk||^2

        // phase B: cos < 0.5 <=> num < 0 || num^2 < t2h*fn2 (sqrt/div-free;
        // num=fn2=0 (inactive slot / zero row) -> excluded, matching jnp NaN semantics)
        float4 ssum = make_float4(0.f, 0.f, 0.f, 0.f);
        float scnt = 0.f;
        #pragma unroll
        for (int it = 0; it < 8; ++it) {
            float4 f = fc[it];
            float num = hk.x * f.x + hk.y * f.y + hk.z * f.z + hk.w * f.w;
            float fn2 = f.x * f.x + f.y * f.y + f.z * f.z + f.w * f.w;
            num = red_q(num);
            fn2 = red_q(fn2);
            if (num < 0.f || num * num < t2h * fn2) {
                ssum.x += f.x; ssum.y += f.y; ssum.z += f.z; ssum.w += f.w;
                scnt += (es + it * 8 < deg) ? 1.f : 0.f;   // count real edges only
            }
        }
        for (int i = es + 64; i < deg; i += 8) {     // deg>64 overflow: ~never
            int eid = ovf ? eids_fb[s + start + i] : lsort[start + i];
            float4 f = *(const float4*)&ef[(size_t)eid * E_SIZE + q * 4];
            float num = hk.x * f.x + hk.y * f.y + hk.z * f.z + hk.w * f.w;
            float fn2 = f.x * f.x + f.y * f.y + f.z * f.z + f.w * f.w;
            num = red_q(num);
            fn2 = red_q(fn2);
            if (num < 0.f || num * num < t2h * fn2) {
                ssum.x += f.x; ssum.y += f.y; ssum.z += f.z; ssum.w += f.w;
                scnt += 1.f;
            }
        }
        ssum = red_es4(ssum);
        scnt = red_es(scnt);

        float4 a;
        if (scnt > 0.f) {
            float r = 1.f / scnt;
            a = make_float4(ssum.x * r, ssum.y * r, ssum.z * r, ssum.w * r);
        } else {
            a = hk;
        }
        if (es == 0 && nid < N) *(float4*)&agg[(size_t)nid * E_SIZE + q * 4] = a;
    }
}

// ---------------- GEMM: out[N][128] = [h_in | agg] @ W^T ----------------
// BM=128, BN=64, BK=32; 782 blocks; 256 threads; 8x4 acc per thread.

__global__ __launch_bounds__(256) void k_gemm(
    const float* __restrict__ A0,   // h_in [N][128]
    const float* __restrict__ A1,   // agg  [N][32]
    const float* __restrict__ W,    // [128][160]
    float* __restrict__ out, int N)
{
    __shared__ float As[128][33];   // +1 pad: a-reads conflict-free
    __shared__ float Bs[32][68];    // transposed W half-chunk; stride 68 floats (16B-aligned)
    int t = threadIdx.x;
    int m0 = (blockIdx.x >> 1) * 128;
    int c0 = (blockIdx.x & 1) * 64;
    int tn = t & 15, tm = t >> 4;
    float acc[8][4];
    #pragma unroll
    for (int r = 0; r < 8; ++r)
        #pragma unroll
        for (int c = 0; c < 4; ++c) acc[r][c] = 0.f;

    int hl = t & 63;                // W-row within the 64-col half
    int kg = t >> 6;                // k-octet 0..3

    for (int chunk = 0; chunk < 5; ++chunk) {
        #pragma unroll
        for (int l = 0; l < 4; ++l) {
            int id = l * 256 + t;          // 0..1023 float4 slots
            int r = id >> 3;               // 0..127
            int qq = id & 7;               // float4 col within 32
            int m = m0 + r;
            float4 v = make_float4(0.f, 0.f, 0.f, 0.f);
            if (m < N) {
                if (chunk < 4) v = *(const float4*)&A0[(size_t)m * IN_SIZE + chunk * 32 + qq * 4];
                else           v = *(const float4*)&A1[(size_t)m * E_SIZE + qq * 4];
            }
            As[r][qq * 4 + 0] = v.x; As[r][qq * 4 + 1] = v.y;
            As[r][qq * 4 + 2] = v.z; As[r][qq * 4 + 3] = v.w;
        }
        {
            const float* wrow = &W[(size_t)(c0 + hl) * KDIM + chunk * 32 + kg * 8];
            float4 v0 = *(const float4*)&wrow[0];
            float4 v1 = *(const float4*)&wrow[4];
            int k0 = kg * 8;
            Bs[k0 + 0][hl] = v0.x; Bs[k0 + 1][hl] = v0.y;
            Bs[k0 + 2][hl] = v0.z; Bs[k0 + 3][hl] = v0.w;
            Bs[k0 + 4][hl] = v1.x; Bs[k0 + 5][hl] = v1.y;
            Bs[k0 + 6][hl] = v1.z; Bs[k0 + 7][hl] = v1.w;
        }
        __syncthreads();
        #pragma unroll 4
        for (int kk = 0; kk < 32; ++kk) {
            float a[8];
            #pragma unroll
            for (int r = 0; r < 8; ++r) a[r] = As[tm * 8 + r][kk];
            float4 bb = *(const float4*)&Bs[kk][tn * 4];
            #pragma unroll
            for (int r = 0; r < 8; ++r) {
                acc[r][0] = fmaf(a[r], bb.x, acc[r][0]);
                acc[r][1] = fmaf(a[r], bb.y, acc[r][1]);
                acc[r][2] = fmaf(a[r], bb.z, acc[r][2]);
                acc[r][3] = fmaf(a[r], bb.w, acc[r][3]);
            }
        }
        __syncthreads();
    }
    #pragma unroll
    for (int r = 0; r < 8; ++r) {
        int m = m0 + tm * 8 + r;
        if (m < N) {
            float4 o = make_float4(acc[r][0], acc[r][1], acc[r][2], acc[r][3]);
            *(float4*)&out[(size_t)m * IN_SIZE + c0 + tn * 4] = o;
        }
    }
}

// ---------------- launch ----------------

extern "C" void kernel_launch(void* const* d_in, const int* in_sizes, int n_in,
                              void* d_out, int out_size, void* d_ws, size_t ws_size,
                              hipStream_t stream) {
    const float* h_in = (const float*)d_in[0];
    const float* ef   = (const float*)d_in[1];
    const int*   dst  = (const int*)d_in[2];
    const float* W    = (const float*)d_in[3];
    float* out = (float*)d_out;
    int N = in_sizes[0] / IN_SIZE;     // 50000
    int E = in_sizes[2];               // 1600000
    int nbk = (N + BNODES - 1) >> BSHIFT;   // 782 buckets (<= NBK_MAX)

    // workspace carve-out (256B aligned)
    char* p = (char*)d_ws;
    auto take = [&](size_t bytes) { char* r = p; p += (bytes + 255) & ~(size_t)255; return r; };
    int*   slabA   = (int*)take((size_t)NSCAT * nbk * 4);
    int*   slabB   = (int*)take((size_t)NSCAT * nbk * 4);
    int*   bktbase = (int*)take((size_t)(nbk + 1) * 4);
    int*   binb    = (int*)take((size_t)E * 4);
    int*   eidsfb  = (int*)take((size_t)E * 4);   // overflow fallback only
    float* agg     = (float*)take((size_t)N * E_SIZE * 4);

    k_bhist    <<<NSCAT, 256, 0, stream>>>(dst, slabA, E, nbk);
    k_scan     <<<1, 1024, 0, stream>>>(slabA, slabB, bktbase, nbk, E);
    k_scatter  <<<NSCAT, 256, 0, stream>>>(dst, slabB, binb, E, nbk);
    k_fill_node<<<nbk, 512, 0, stream>>>(bktbase, binb, ef, eidsfb, agg, N);
    k_gemm     <<<((N + 127) / 128) * 2, 256, 0, stream>>>(h_in, agg, W, out, N);
}

// Round 8
// 134.196 us; speedup vs baseline: 1.3982x; 1.3982x over previous
//
#include <hip/hip_runtime.h>
#include <math.h>

#define IN_SIZE 128
#define E_SIZE  32
#define KDIM    160
#define BSHIFT  6                    // 64 nodes per bucket
#define BNODES  (1 << BSHIFT)
#define NBK_MAX 1024                 // nbk = ceil(50000/64) = 782 <= 1024
#define NSCAT   256                  // blocks for hist/scatter (== threads in k_scan1)

// ---------------- per-block bucket histogram -> slab (no global atomics) ----------------

__global__ __launch_bounds__(256) void k_bhist(
    const int* __restrict__ dst, int* __restrict__ slabA, int E, int nbk)
{
    __shared__ int hist[NBK_MAX];
    int tid = threadIdx.x;
    for (int k = tid; k < nbk; k += 256) hist[k] = 0;
    __syncthreads();
    int chunk = (E + NSCAT - 1) / NSCAT;
    int s = blockIdx.x * chunk;
    int e = s + chunk; if (e > E) e = E;
    for (int i = s + tid; i < e; i += 256)
        atomicAdd(&hist[dst[i] >> BSHIFT], 1);
    __syncthreads();
    for (int k = tid; k < nbk; k += 256)
        slabA[blockIdx.x * nbk + k] = hist[k];
}

// ---------------- scan stage 1: per-bucket prefix over the 256 block counts ----------------
// one block per bucket (parallel across 782 CUs — never a single-CU megabyte scan)

__global__ __launch_bounds__(NSCAT) void k_scan1(
    const int* __restrict__ slabA, int* __restrict__ slabB,
    int* __restrict__ bktcnt, int nbk)
{
    __shared__ int s[NSCAT];
    int k = blockIdx.x, t = threadIdx.x;
    int v = slabA[t * nbk + k];
    s[t] = v;
    __syncthreads();
    for (int off = 1; off < NSCAT; off <<= 1) {     // Hillis-Steele inclusive
        int add = (t >= off) ? s[t - off] : 0;
        __syncthreads();
        s[t] += add;
        __syncthreads();
    }
    slabB[t * nbk + k] = s[t] - v;                  // exclusive within-bucket base for block t
    if (t == NSCAT - 1) bktcnt[k] = s[t];
}

// ---------------- scan stage 2: bucket bases (tiny: 782 ints) ----------------

__global__ __launch_bounds__(1024) void k_scan2(
    const int* __restrict__ bktcnt, int* __restrict__ bktbase, int nbk, int E)
{
    __shared__ int s[1024];
    int tid = threadIdx.x;
    int v = (tid < nbk) ? bktcnt[tid] : 0;
    s[tid] = v;
    __syncthreads();
    for (int off = 1; off < 1024; off <<= 1) {
        int add = (tid >= off) ? s[tid - off] : 0;
        __syncthreads();
        s[tid] += add;
        __syncthreads();
    }
    if (tid < nbk) bktbase[tid] = s[tid] - v;       // exclusive
    if (tid == 0) bktbase[nbk] = E;
}

// ---------------- scatter with precomputed bases (single dst pass, LDS cursors) ----------------
// bin entry packs (edge_id << 6) | (dst & 63); eid < 2^21 fits in 27 bits.

__global__ __launch_bounds__(256) void k_scatter(
    const int* __restrict__ dst, const int* __restrict__ slabB,
    const int* __restrict__ bktbase, int* __restrict__ bin, int E, int nbk)
{
    __shared__ int cur[NBK_MAX];
    int tid = threadIdx.x;
    for (int k = tid; k < nbk; k += 256)
        cur[k] = bktbase[k] + slabB[blockIdx.x * nbk + k];
    __syncthreads();
    int chunk = (E + NSCAT - 1) / NSCAT;
    int s = blockIdx.x * chunk;
    int e = s + chunk; if (e > E) e = E;
    for (int i = s + tid; i < e; i += 256) {
        int d = dst[i];
        int p = atomicAdd(&cur[d >> BSHIFT], 1);    // cursor holds GLOBAL position
        bin[p] = (i << BSHIFT) | (d & (BNODES - 1));
    }
}

// ---------------- per-bucket exact placement + offsets ----------------

__global__ __launch_bounds__(256) void k_fill3(
    const int* __restrict__ bktbase, const int* __restrict__ bin,
    int* __restrict__ eids, int* __restrict__ offsets, int N)
{
    __shared__ int cnt[BNODES];
    __shared__ int nb0[BNODES];
    int b = blockIdx.x;
    int n0 = b << BSHIFT;
    int tid = threadIdx.x;
    int s = bktbase[b];
    int e = bktbase[b + 1];
    if (tid < BNODES) cnt[tid] = 0;
    __syncthreads();
    for (int k = s + tid; k < e; k += 256)
        atomicAdd(&cnt[bin[k] & (BNODES - 1)], 1);
    __syncthreads();
    if (tid < BNODES) {                         // wave 0: shuffle scan of 64 degs
        int v = cnt[tid];
        int x = v;
        #pragma unroll
        for (int off = 1; off < 64; off <<= 1) {
            int y = __shfl_up(x, off);
            if (tid >= off) x += y;
        }
        int nodebase = s + x - v;               // exclusive
        nb0[tid] = nodebase;
        if (n0 + tid < N) offsets[n0 + tid] = nodebase;
        cnt[tid] = 0;                           // reuse as cursor
    }
    __syncthreads();
    for (int k = s + tid; k < e; k += 256) {
        int pk = bin[k];
        int ln = pk & (BNODES - 1);
        int p = nb0[ln] + atomicAdd(&cnt[ln], 1);
        eids[p] = pk >> BSHIFT;
    }
    if (b == 0 && tid == 0) offsets[N] = bktbase[(N + BNODES - 1) >> BSHIFT];
}

// ---------------- per-node aggregate (1 wave / node, 8 edges x 8 float4-lanes) ----------------
// lane = es*8 + q : es = edge slot (0..7), q = feature quarter (owns features q*4..q*4+3).

__device__ __forceinline__ float red_q(float x) {        // sum across q (lane bits 0..2)
    x += __shfl_xor(x, 1); x += __shfl_xor(x, 2); x += __shfl_xor(x, 4);
    return x;
}
__device__ __forceinline__ float red_es(float x) {       // sum across es (lane bits 3..5)
    x += __shfl_xor(x, 8); x += __shfl_xor(x, 16); x += __shfl_xor(x, 32);
    return x;
}
__device__ __forceinline__ float4 red_es4(float4 v) {
    v.x = red_es(v.x); v.y = red_es(v.y); v.z = red_es(v.z); v.w = red_es(v.w);
    return v;
}

__global__ __launch_bounds__(256, 6) void k_node(
    const float* __restrict__ ef, const int* __restrict__ offsets,
    const int* __restrict__ eids, float* __restrict__ agg, int N)
{
    int wid = blockIdx.x * 4 + (threadIdx.x >> 6);   // node id
    if (wid >= N) return;
    int lane = threadIdx.x & 63;
    int es = lane >> 3;
    int q  = lane & 7;
    int start = offsets[wid];
    int deg   = offsets[wid + 1] - start;

    // one coalesced eid load per lane; distribute via shfl
    int myeid = (lane < deg) ? eids[start + lane] : 0;

    // preload up to 8 edge rows per slot into registers (static indices — stays in VGPRs)
    float4 fc[8];
    #pragma unroll
    for (int it = 0; it < 8; ++it) {
        int i = es + it * 8;
        int eid = __shfl(myeid, i);
        float4 f = make_float4(0.f, 0.f, 0.f, 0.f);
        if (i < deg)                        // uniform within each 8-lane q-group
            f = *(const float4*)&ef[(size_t)eid * E_SIZE + q * 4];
        fc[it] = f;
    }

    // phase A: per-feature sum over in-edges
    float4 esum = make_float4(0.f, 0.f, 0.f, 0.f);
    #pragma unroll
    for (int it = 0; it < 8; ++it) {
        esum.x += fc[it].x; esum.y += fc[it].y; esum.z += fc[it].z; esum.w += fc[it].w;
    }
    for (int i = es + 64; i < deg; i += 8) {            // overflow (deg>64): ~never
        int eid = eids[start + i];
        float4 f = *(const float4*)&ef[(size_t)eid * E_SIZE + q * 4];
        esum.x += f.x; esum.y += f.y; esum.z += f.z; esum.w += f.w;
    }
    esum = red_es4(esum);
    float inv = (deg > 0) ? 1.f / (float)deg : 0.f;
    float4 hk = make_float4(esum.x * inv, esum.y * inv, esum.z * inv, esum.w * inv);
    float hn2 = hk.x * hk.x + hk.y * hk.y + hk.z * hk.z + hk.w * hk.w;
    hn2 = red_q(hn2);                                   // ||hk||^2, all lanes
    float t2h = 0.25f * hn2;                            // THRESH^2 * ||hk||^2

    // phase B: cos < 0.5  <=>  num < 0  ||  num^2 < 0.25*hn2*fn2   (sqrt/div-free;
    // num=fn2=0 (inactive slot / zero row) -> excluded, matching jnp's NaN semantics)
    float4 ssum = make_float4(0.f, 0.f, 0.f, 0.f);
    float scnt = 0.f;
    #pragma unroll
    for (int it = 0; it < 8; ++it) {
        float4 f = fc[it];
        float num = hk.x * f.x + hk.y * f.y + hk.z * f.z + hk.w * f.w;
        float fn2 = f.x * f.x + f.y * f.y + f.z * f.z + f.w * f.w;
        num = red_q(num);
        fn2 = red_q(fn2);
        if (num < 0.f || num * num < t2h * fn2) {
            ssum.x += f.x; ssum.y += f.y; ssum.z += f.z; ssum.w += f.w;
            scnt += (es + it * 8 < deg) ? 1.f : 0.f;    // count real edges only (f=0 adds 0 to ssum)
        }
    }
    for (int i = es + 64; i < deg; i += 8) {            // overflow (deg>64): ~never
        int eid = eids[start + i];
        float4 f = *(const float4*)&ef[(size_t)eid * E_SIZE + q * 4];
        float num = hk.x * f.x + hk.y * f.y + hk.z * f.z + hk.w * f.w;
        float fn2 = f.x * f.x + f.y * f.y + f.z * f.z + f.w * f.w;
        num = red_q(num);
        fn2 = red_q(fn2);
        if (num < 0.f || num * num < t2h * fn2) {
            ssum.x += f.x; ssum.y += f.y; ssum.z += f.z; ssum.w += f.w;
            scnt += 1.f;
        }
    }
    ssum = red_es4(ssum);
    scnt = red_es(scnt);

    float4 a;
    if (scnt > 0.f) {
        float r = 1.f / scnt;
        a = make_float4(ssum.x * r, ssum.y * r, ssum.z * r, ssum.w * r);
    } else {
        a = hk;
    }
    if (es == 0) *(float4*)&agg[(size_t)wid * E_SIZE + q * 4] = a;
}

// ---------------- GEMM: out[N][128] = [h_in | agg] @ W^T ----------------
// BM=128, BN=64, BK=32; 782 blocks; 256 threads; 8x4 acc per thread.

__global__ __launch_bounds__(256) void k_gemm(
    const float* __restrict__ A0,   // h_in [N][128]
    const float* __restrict__ A1,   // agg  [N][32]
    const float* __restrict__ W,    // [128][160]
    float* __restrict__ out, int N)
{
    __shared__ float As[128][33];   // +1 pad: a-reads conflict-free
    __shared__ float Bs[32][68];    // transposed W half-chunk; stride 68 floats (16B-aligned)
    int t = threadIdx.x;
    int m0 = (blockIdx.x >> 1) * 128;
    int c0 = (blockIdx.x & 1) * 64;
    int tn = t & 15, tm = t >> 4;
    float acc[8][4];
    #pragma unroll
    for (int r = 0; r < 8; ++r)
        #pragma unroll
        for (int c = 0; c < 4; ++c) acc[r][c] = 0.f;

    int hl = t & 63;                // W-row within the 64-col half
    int kg = t >> 6;                // k-octet 0..3

    for (int chunk = 0; chunk < 5; ++chunk) {
        #pragma unroll
        for (int l = 0; l < 4; ++l) {
            int id = l * 256 + t;          // 0..1023 float4 slots
            int r = id >> 3;               // 0..127
            int qq = id & 7;               // float4 col within 32
            int m = m0 + r;
            float4 v = make_float4(0.f, 0.f, 0.f, 0.f);
            if (m < N) {
                if (chunk < 4) v = *(const float4*)&A0[(size_t)m * IN_SIZE + chunk * 32 + qq * 4];
                else           v = *(const float4*)&A1[(size_t)m * E_SIZE + qq * 4];
            }
            As[r][qq * 4 + 0] = v.x; As[r][qq * 4 + 1] = v.y;
            As[r][qq * 4 + 2] = v.z; As[r][qq * 4 + 3] = v.w;
        }
        {
            const float* wrow = &W[(size_t)(c0 + hl) * KDIM + chunk * 32 + kg * 8];
            float4 v0 = *(const float4*)&wrow[0];
            float4 v1 = *(const float4*)&wrow[4];
            int k0 = kg * 8;
            Bs[k0 + 0][hl] = v0.x; Bs[k0 + 1][hl] = v0.y;
            Bs[k0 + 2][hl] = v0.z; Bs[k0 + 3][hl] = v0.w;
            Bs[k0 + 4][hl] = v1.x; Bs[k0 + 5][hl] = v1.y;
            Bs[k0 + 6][hl] = v1.z; Bs[k0 + 7][hl] = v1.w;
        }
        __syncthreads();
        #pragma unroll 4
        for (int kk = 0; kk < 32; ++kk) {
            float a[8];
            #pragma unroll
            for (int r = 0; r < 8; ++r) a[r] = As[tm * 8 + r][kk];
            float4 bb = *(const float4*)&Bs[kk][tn * 4];
            #pragma unroll
            for (int r = 0; r < 8; ++r) {
                acc[r][0] = fmaf(a[r], bb.x, acc[r][0]);
                acc[r][1] = fmaf(a[r], bb.y, acc[r][1]);
                acc[r][2] = fmaf(a[r], bb.z, acc[r][2]);
                acc[r][3] = fmaf(a[r], bb.w, acc[r][3]);
            }
        }
        __syncthreads();
    }
    #pragma unroll
    for (int r = 0; r < 8; ++r) {
        int m = m0 + tm * 8 + r;
        if (m < N) {
            float4 o = make_float4(acc[r][0], acc[r][1], acc[r][2], acc[r][3]);
            *(float4*)&out[(size_t)m * IN_SIZE + c0 + tn * 4] = o;
        }
    }
}

// ---------------- launch ----------------

extern "C" void kernel_launch(void* const* d_in, const int* in_sizes, int n_in,
                              void* d_out, int out_size, void* d_ws, size_t ws_size,
                              hipStream_t stream) {
    const float* h_in = (const float*)d_in[0];
    const float* ef   = (const float*)d_in[1];
    const int*   dst  = (const int*)d_in[2];
    const float* W    = (const float*)d_in[3];
    float* out = (float*)d_out;
    int N = in_sizes[0] / IN_SIZE;     // 50000
    int E = in_sizes[2];               // 1600000
    int nbk = (N + BNODES - 1) >> BSHIFT;   // 782 buckets (<= NBK_MAX)

    // workspace carve-out (256B aligned)
    char* p = (char*)d_ws;
    auto take = [&](size_t bytes) { char* r = p; p += (bytes + 255) & ~(size_t)255; return r; };
    int*   slabA   = (int*)take((size_t)NSCAT * nbk * 4);
    int*   slabB   = (int*)take((size_t)NSCAT * nbk * 4);
    int*   bktcnt  = (int*)take((size_t)nbk * 4);
    int*   bktbase = (int*)take((size_t)(nbk + 1) * 4);
    int*   offsets = (int*)take((size_t)(N + 1) * 4);
    int*   binb    = (int*)take((size_t)E * 4);
    int*   eidsb   = (int*)take((size_t)E * 4);
    float* agg     = (float*)take((size_t)N * E_SIZE * 4);

    k_bhist  <<<NSCAT, 256, 0, stream>>>(dst, slabA, E, nbk);
    k_scan1  <<<nbk, NSCAT, 0, stream>>>(slabA, slabB, bktcnt, nbk);
    k_scan2  <<<1, 1024, 0, stream>>>(bktcnt, bktbase, nbk, E);
    k_scatter<<<NSCAT, 256, 0, stream>>>(dst, slabB, bktbase, binb, E, nbk);
    k_fill3  <<<nbk, 256, 0, stream>>>(bktbase, binb, eidsb, offsets, N);
    k_node   <<<(N + 3) / 4, 256, 0, stream>>>(ef, offsets, eidsb, agg, N);
    k_gemm   <<<((N + 127) / 128) * 2, 256, 0, stream>>>(h_in, agg, W, out, N);
}

// Round 9
// 126.874 us; speedup vs baseline: 1.4788x; 1.0577x over previous
//
#include <hip/hip_runtime.h>
#include <math.h>

#define IN_SIZE 128
#define E_SIZE  32
#define KDIM    160
#define BSHIFT  6                    // 64 nodes per bucket
#define BNODES  (1 << BSHIFT)
#define NBK_MAX 1024                 // nbk = ceil(50000/64) = 782 <= 1024
#define NSCAT   256                  // blocks for hist/scatter (== threads in k_scan1)

// ---------------- per-block bucket histogram -> slab (no global atomics) ----------------

__global__ __launch_bounds__(256) void k_bhist(
    const int* __restrict__ dst, int* __restrict__ slabA, int E, int nbk)
{
    __shared__ int hist[NBK_MAX];
    int tid = threadIdx.x;
    for (int k = tid; k < nbk; k += 256) hist[k] = 0;
    __syncthreads();
    int chunk = (E + NSCAT - 1) / NSCAT;
    int s = blockIdx.x * chunk;
    int e = s + chunk; if (e > E) e = E;
    for (int i = s + tid; i < e; i += 256)
        atomicAdd(&hist[dst[i] >> BSHIFT], 1);
    __syncthreads();
    for (int k = tid; k < nbk; k += 256)
        slabA[blockIdx.x * nbk + k] = hist[k];
}

// ---------------- scan stage 1: per-bucket prefix over the 256 block counts ----------------

__global__ __launch_bounds__(NSCAT) void k_scan1(
    const int* __restrict__ slabA, int* __restrict__ slabB,
    int* __restrict__ bktcnt, int nbk)
{
    __shared__ int s[NSCAT];
    int k = blockIdx.x, t = threadIdx.x;
    int v = slabA[t * nbk + k];
    s[t] = v;
    __syncthreads();
    for (int off = 1; off < NSCAT; off <<= 1) {     // Hillis-Steele inclusive
        int add = (t >= off) ? s[t - off] : 0;
        __syncthreads();
        s[t] += add;
        __syncthreads();
    }
    slabB[t * nbk + k] = s[t] - v;                  // exclusive within-bucket base for block t
    if (t == NSCAT - 1) bktcnt[k] = s[t];
}

// ---------------- fast in-LDS exclusive scan of bktcnt (1024 slots, 256 thr, 4/thread) ----
// result left in base[]; used by k_scatter (which also publishes bktbase for k_fill3).

__device__ __forceinline__ void block_scan_bktcnt(
    const int* __restrict__ bktcnt, int nbk, int* base /*LDS[NBK_MAX]*/, int* wtot /*LDS[4]*/)
{
    int tid = threadIdx.x;
    int lane = tid & 63, wv = tid >> 6;
    int k0 = tid * 4;
    int v0 = (k0 + 0 < nbk) ? bktcnt[k0 + 0] : 0;
    int v1 = (k0 + 1 < nbk) ? bktcnt[k0 + 1] : 0;
    int v2 = (k0 + 2 < nbk) ? bktcnt[k0 + 2] : 0;
    int v3 = (k0 + 3 < nbk) ? bktcnt[k0 + 3] : 0;
    int tsum = v0 + v1 + v2 + v3;
    int x = tsum;
    #pragma unroll
    for (int off = 1; off < 64; off <<= 1) {
        int y = __shfl_up(x, off);
        if (lane >= off) x += y;
    }
    if (lane == 63) wtot[wv] = x;
    __syncthreads();
    if (tid == 0) {
        int r = 0;
        #pragma unroll
        for (int w = 0; w < 4; ++w) { int t = wtot[w]; wtot[w] = r; r += t; }
    }
    __syncthreads();
    int ex = wtot[wv] + (x - tsum);                 // exclusive base of element k0
    base[k0 + 0] = ex;
    base[k0 + 1] = ex + v0;
    base[k0 + 2] = ex + v0 + v1;
    base[k0 + 3] = ex + v0 + v1 + v2;
    __syncthreads();
}

// ---------------- scatter (single dst pass, LDS cursors; also publishes bktbase) --------
// bin entry packs (edge_id << 6) | (dst & 63); eid < 2^21 fits in 27 bits.

__global__ __launch_bounds__(256) void k_scatter(
    const int* __restrict__ dst, const int* __restrict__ slabB,
    const int* __restrict__ bktcnt, int* __restrict__ bktbase,
    int* __restrict__ bin, int E, int nbk)
{
    __shared__ int base[NBK_MAX];
    __shared__ int wtot[4];
    __shared__ int cur[NBK_MAX];
    int tid = threadIdx.x;
    block_scan_bktcnt(bktcnt, nbk, base, wtot);
    for (int k = tid; k < nbk; k += 256)
        cur[k] = base[k] + slabB[blockIdx.x * nbk + k];
    if (blockIdx.x == 0) {                          // publish bucket bases for k_fill3
        for (int k = tid; k < nbk; k += 256) bktbase[k] = base[k];
        if (tid == 0) bktbase[nbk] = E;
    }
    __syncthreads();
    int chunk = (E + NSCAT - 1) / NSCAT;
    int s = blockIdx.x * chunk;
    int e = s + chunk; if (e > E) e = E;
    for (int i = s + tid; i < e; i += 256) {
        int d = dst[i];
        int p = atomicAdd(&cur[d >> BSHIFT], 1);    // cursor holds GLOBAL position
        bin[p] = (i << BSHIFT) | (d & (BNODES - 1));
    }
}

// ---------------- per-bucket exact placement + offsets ----------------

__global__ __launch_bounds__(256) void k_fill3(
    const int* __restrict__ bktbase, const int* __restrict__ bin,
    int* __restrict__ eids, int* __restrict__ offsets, int N)
{
    __shared__ int cnt[BNODES];
    __shared__ int nb0[BNODES];
    int b = blockIdx.x;
    int n0 = b << BSHIFT;
    int tid = threadIdx.x;
    int s = bktbase[b];
    int e = bktbase[b + 1];
    if (tid < BNODES) cnt[tid] = 0;
    __syncthreads();
    for (int k = s + tid; k < e; k += 256)
        atomicAdd(&cnt[bin[k] & (BNODES - 1)], 1);
    __syncthreads();
    if (tid < BNODES) {                         // wave 0: shuffle scan of 64 degs
        int v = cnt[tid];
        int x = v;
        #pragma unroll
        for (int off = 1; off < 64; off <<= 1) {
            int y = __shfl_up(x, off);
            if (tid >= off) x += y;
        }
        int nodebase = s + x - v;               // exclusive
        nb0[tid] = nodebase;
        if (n0 + tid < N) offsets[n0 + tid] = nodebase;
        cnt[tid] = 0;                           // reuse as cursor
    }
    __syncthreads();
    for (int k = s + tid; k < e; k += 256) {
        int pk = bin[k];
        int ln = pk & (BNODES - 1);
        int p = nb0[ln] + atomicAdd(&cnt[ln], 1);
        eids[p] = pk >> BSHIFT;
    }
    if (b == 0 && tid == 0) offsets[N] = bktbase[(N + BNODES - 1) >> BSHIFT];
}

// ---------------- per-node aggregate (1 wave / node, 8 edges x 8 float4-lanes) ----------------
// lane = es*8 + q : es = edge slot (0..7), q = feature quarter (owns features q*4..q*4+3).
// Deg-adaptive: NIT=4 slots for deg<=32 (~55% of nodes — halves dead VALU), NIT=8 for deg<=64,
// dynamic overflow loop beyond (~never).

__device__ __forceinline__ float red_q(float x) {        // sum across q (lane bits 0..2)
    x += __shfl_xor(x, 1); x += __shfl_xor(x, 2); x += __shfl_xor(x, 4);
    return x;
}
__device__ __forceinline__ float red_es(float x) {       // sum across es (lane bits 3..5)
    x += __shfl_xor(x, 8); x += __shfl_xor(x, 16); x += __shfl_xor(x, 32);
    return x;
}
__device__ __forceinline__ float4 red_es4(float4 v) {
    v.x = red_es(v.x); v.y = red_es(v.y); v.z = red_es(v.z); v.w = red_es(v.w);
    return v;
}

template<int NIT>
__device__ __forceinline__ float4 node_aggregate(
    const float* __restrict__ ef, const int* __restrict__ eids,
    int start, int deg, int lane, int es, int q)
{
    // one coalesced eid load per lane; distribute via shfl
    int myeid = (lane < deg) ? eids[start + lane] : 0;

    float4 fc[NIT];
    #pragma unroll
    for (int it = 0; it < NIT; ++it) {
        int i = es + it * 8;
        int eid = __shfl(myeid, i);
        float4 f = make_float4(0.f, 0.f, 0.f, 0.f);
        if (i < deg)                        // uniform within each 8-lane q-group
            f = *(const float4*)&ef[(size_t)eid * E_SIZE + q * 4];
        fc[it] = f;
    }

    // phase A: per-feature sum over in-edges
    float4 esum = make_float4(0.f, 0.f, 0.f, 0.f);
    #pragma unroll
    for (int it = 0; it < NIT; ++it) {
        esum.x += fc[it].x; esum.y += fc[it].y; esum.z += fc[it].z; esum.w += fc[it].w;
    }
    for (int i = es + NIT * 8; i < deg; i += 8) {       // overflow: ~never
        int eid = eids[start + i];
        float4 f = *(const float4*)&ef[(size_t)eid * E_SIZE + q * 4];
        esum.x += f.x; esum.y += f.y; esum.z += f.z; esum.w += f.w;
    }
    esum = red_es4(esum);
    float inv = (deg > 0) ? 1.f / (float)deg : 0.f;
    float4 hk = make_float4(esum.x * inv, esum.y * inv, esum.z * inv, esum.w * inv);
    float hn2 = hk.x * hk.x + hk.y * hk.y + hk.z * hk.z + hk.w * hk.w;
    hn2 = red_q(hn2);                                   // ||hk||^2, all lanes
    float t2h = 0.25f * hn2;                            // THRESH^2 * ||hk||^2

    // phase B: cos < 0.5  <=>  num < 0  ||  num^2 < 0.25*hn2*fn2   (sqrt/div-free;
    // num=fn2=0 (inactive slot / zero row) -> excluded, matching jnp's NaN semantics)
    float4 ssum = make_float4(0.f, 0.f, 0.f, 0.f);
    float scnt = 0.f;
    #pragma unroll
    for (int it = 0; it < NIT; ++it) {
        float4 f = fc[it];
        float num = hk.x * f.x + hk.y * f.y + hk.z * f.z + hk.w * f.w;
        float fn2 = f.x * f.x + f.y * f.y + f.z * f.z + f.w * f.w;
        num = red_q(num);
        fn2 = red_q(fn2);
        if (num < 0.f || num * num < t2h * fn2) {
            ssum.x += f.x; ssum.y += f.y; ssum.z += f.z; ssum.w += f.w;
            scnt += (es + it * 8 < deg) ? 1.f : 0.f;    // count real edges only
        }
    }
    for (int i = es + NIT * 8; i < deg; i += 8) {       // overflow: ~never
        int eid = eids[start + i];
        float4 f = *(const float4*)&ef[(size_t)eid * E_SIZE + q * 4];
        float num = hk.x * f.x + hk.y * f.y + hk.z * f.z + hk.w * f.w;
        float fn2 = f.x * f.x + f.y * f.y + f.z * f.z + f.w * f.w;
        num = red_q(num);
        fn2 = red_q(fn2);
        if (num < 0.f || num * num < t2h * fn2) {
            ssum.x += f.x; ssum.y += f.y; ssum.z += f.z; ssum.w += f.w;
            scnt += 1.f;
        }
    }
    ssum = red_es4(ssum);
    scnt = red_es(scnt);

    float4 a;
    if (scnt > 0.f) {
        float r = 1.f / scnt;
        a = make_float4(ssum.x * r, ssum.y * r, ssum.z * r, ssum.w * r);
    } else {
        a = hk;
    }
    return a;
}

__global__ __launch_bounds__(256, 6) void k_node(
    const float* __restrict__ ef, const int* __restrict__ offsets,
    const int* __restrict__ eids, float* __restrict__ agg, int N)
{
    int wid = blockIdx.x * 4 + (threadIdx.x >> 6);   // node id
    if (wid >= N) return;
    int lane = threadIdx.x & 63;
    int es = lane >> 3;
    int q  = lane & 7;
    int start = offsets[wid];
    int deg   = offsets[wid + 1] - start;

    float4 a;
    if (deg <= 32) a = node_aggregate<4>(ef, eids, start, deg, lane, es, q);
    else           a = node_aggregate<8>(ef, eids, start, deg, lane, es, q);

    if (es == 0) *(float4*)&agg[(size_t)wid * E_SIZE + q * 4] = a;
}

// ---------------- GEMM: out[N][128] = [h_in | agg] @ W^T ----------------
// BM=128, BN=64, BK=32; 782 blocks; 256 threads; 8x4 acc per thread.

__global__ __launch_bounds__(256) void k_gemm(
    const float* __restrict__ A0,   // h_in [N][128]
    const float* __restrict__ A1,   // agg  [N][32]
    const float* __restrict__ W,    // [128][160]
    float* __restrict__ out, int N)
{
    __shared__ float As[128][33];   // +1 pad: a-reads conflict-free
    __shared__ float Bs[32][68];    // transposed W half-chunk; stride 68 floats (16B-aligned)
    int t = threadIdx.x;
    int m0 = (blockIdx.x >> 1) * 128;
    int c0 = (blockIdx.x & 1) * 64;
    int tn = t & 15, tm = t >> 4;
    float acc[8][4];
    #pragma unroll
    for (int r = 0; r < 8; ++r)
        #pragma unroll
        for (int c = 0; c < 4; ++c) acc[r][c] = 0.f;

    int hl = t & 63;                // W-row within the 64-col half
    int kg = t >> 6;                // k-octet 0..3

    for (int chunk = 0; chunk < 5; ++chunk) {
        #pragma unroll
        for (int l = 0; l < 4; ++l) {
            int id = l * 256 + t;          // 0..1023 float4 slots
            int r = id >> 3;               // 0..127
            int qq = id & 7;               // float4 col within 32
            int m = m0 + r;
            float4 v = make_float4(0.f, 0.f, 0.f, 0.f);
            if (m < N) {
                if (chunk < 4) v = *(const float4*)&A0[(size_t)m * IN_SIZE + chunk * 32 + qq * 4];
                else           v = *(const float4*)&A1[(size_t)m * E_SIZE + qq * 4];
            }
            As[r][qq * 4 + 0] = v.x; As[r][qq * 4 + 1] = v.y;
            As[r][qq * 4 + 2] = v.z; As[r][qq * 4 + 3] = v.w;
        }
        {
            const float* wrow = &W[(size_t)(c0 + hl) * KDIM + chunk * 32 + kg * 8];
            float4 v0 = *(const float4*)&wrow[0];
            float4 v1 = *(const float4*)&wrow[4];
            int k0 = kg * 8;
            Bs[k0 + 0][hl] = v0.x; Bs[k0 + 1][hl] = v0.y;
            Bs[k0 + 2][hl] = v0.z; Bs[k0 + 3][hl] = v0.w;
            Bs[k0 + 4][hl] = v1.x; Bs[k0 + 5][hl] = v1.y;
            Bs[k0 + 6][hl] = v1.z; Bs[k0 + 7][hl] = v1.w;
        }
        __syncthreads();
        #pragma unroll 4
        for (int kk = 0; kk < 32; ++kk) {
            float a[8];
            #pragma unroll
            for (int r = 0; r < 8; ++r) a[r] = As[tm * 8 + r][kk];
            float4 bb = *(const float4*)&Bs[kk][tn * 4];
            #pragma unroll
            for (int r = 0; r < 8; ++r) {
                acc[r][0] = fmaf(a[r], bb.x, acc[r][0]);
                acc[r][1] = fmaf(a[r], bb.y, acc[r][1]);
                acc[r][2] = fmaf(a[r], bb.z, acc[r][2]);
                acc[r][3] = fmaf(a[r], bb.w, acc[r][3]);
            }
        }
        __syncthreads();
    }
    #pragma unroll
    for (int r = 0; r < 8; ++r) {
        int m = m0 + tm * 8 + r;
        if (m < N) {
            float4 o = make_float4(acc[r][0], acc[r][1], acc[r][2], acc[r][3]);
            *(float4*)&out[(size_t)m * IN_SIZE + c0 + tn * 4] = o;
        }
    }
}

// ---------------- launch ----------------

extern "C" void kernel_launch(void* const* d_in, const int* in_sizes, int n_in,
                              void* d_out, int out_size, void* d_ws, size_t ws_size,
                              hipStream_t stream) {
    const float* h_in = (const float*)d_in[0];
    const float* ef   = (const float*)d_in[1];
    const int*   dst  = (const int*)d_in[2];
    const float* W    = (const float*)d_in[3];
    float* out = (float*)d_out;
    int N = in_sizes[0] / IN_SIZE;     // 50000
    int E = in_sizes[2];               // 1600000
    int nbk = (N + BNODES - 1) >> BSHIFT;   // 782 buckets (<= NBK_MAX)

    // workspace carve-out (256B aligned)
    char* p = (char*)d_ws;
    auto take = [&](size_t bytes) { char* r = p; p += (bytes + 255) & ~(size_t)255; return r; };
    int*   slabA   = (int*)take((size_t)NSCAT * nbk * 4);
    int*   slabB   = (int*)take((size_t)NSCAT * nbk * 4);
    int*   bktcnt  = (int*)take((size_t)nbk * 4);
    int*   bktbase = (int*)take((size_t)(nbk + 1) * 4);
    int*   offsets = (int*)take((size_t)(N + 1) * 4);
    int*   binb    = (int*)take((size_t)E * 4);
    int*   eidsb   = (int*)take((size_t)E * 4);
    float* agg     = (float*)take((size_t)N * E_SIZE * 4);

    k_bhist  <<<NSCAT, 256, 0, stream>>>(dst, slabA, E, nbk);
    k_scan1  <<<nbk, NSCAT, 0, stream>>>(slabA, slabB, bktcnt, nbk);
    k_scatter<<<NSCAT, 256, 0, stream>>>(dst, slabB, bktcnt, bktbase, binb, E, nbk);
    k_fill3  <<<nbk, 256, 0, stream>>>(bktbase, binb, eidsb, offsets, N);
    k_node   <<<(N + 3) / 4, 256, 0, stream>>>(ef, offsets, eidsb, agg, N);
    k_gemm   <<<((N + 127) / 128) * 2, 256, 0, stream>>>(h_in, agg, W, out, N);
}